// Round 4
// baseline (85.551 us; speedup 1.0000x reference)
//
#include <hip/hip_runtime.h>

// Pairlist: 1024 molecules x 100 atoms, all ordered pairs i != j.
// 9900 pairs/molecule, NP = 10,137,600 pairs.
//
// Output (float32, flat): [0,NP)=i  [NP,2NP)=j  [2NP,3NP)=d  [3NP,6NP)=r_ij
//
// Strategy: ONE thread = ONE float4 at its global id -> single linear
// memset-like store sweep over the whole 243 MB output (no multi-stream
// interleave per wave). Threads recompute whatever their float4 needs;
// compute + position reads (1.2 MB, L2-resident) are far under ceilings.
//
// Section float4 counts: S = NP/4 = 2,534,400 per scalar section (i,j,d),
// r-section = 3*NP/4 = 7,603,200. All are multiples of 256 -> the section
// branch is uniform per block. Total float4s = 15,206,400 = 59,400 blocks.

#define N_MOL 1024
#define APM   100u
#define PPM   9900u                 // pairs per molecule
#define NP    10137600u             // total pairs
#define S4    (NP / 4u)             // float4s per scalar section
#define NB    59400                 // total blocks of 256

__device__ __forceinline__ void pair_decode(unsigned p, unsigned& i, unsigned& j) {
    unsigned m  = p / PPM;
    unsigned r  = p - m * PPM;
    unsigned il = r / 99u;
    unsigned k  = r - il * 99u;
    unsigned jl = k + (k >= il ? 1u : 0u);
    i = m * APM + il;
    j = m * APM + jl;
}

__device__ __forceinline__ float3 pair_r(const float* __restrict__ pos, unsigned p) {
    unsigned i, j;
    pair_decode(p, i, j);
    float xi = pos[3u*i+0u], yi = pos[3u*i+1u], zi = pos[3u*i+2u];
    float xj = pos[3u*j+0u], yj = pos[3u*j+1u], zj = pos[3u*j+2u];
    return make_float3(xj - xi, yj - yi, zj - zi);
}

__global__ __launch_bounds__(256) void pairlist_kernel(
    const float* __restrict__ pos,   // (102400, 3)
    float* __restrict__ out)
{
    unsigned g = blockIdx.x * 256u + threadIdx.x;   // global float4 index
    float4 v;

    if (g < S4) {                       // ---- i indices ----
        unsigned p0 = g * 4u;
        #pragma unroll
        for (int q = 0; q < 4; ++q) {
            unsigned i, j; pair_decode(p0 + q, i, j);
            ((float*)&v)[q] = (float)i;
        }
    } else if (g < 2u*S4) {             // ---- j indices ----
        unsigned p0 = (g - S4) * 4u;
        #pragma unroll
        for (int q = 0; q < 4; ++q) {
            unsigned i, j; pair_decode(p0 + q, i, j);
            ((float*)&v)[q] = (float)j;
        }
    } else if (g < 3u*S4) {             // ---- d_ij ----
        unsigned p0 = (g - 2u*S4) * 4u;
        #pragma unroll
        for (int q = 0; q < 4; ++q) {
            float3 r = pair_r(pos, p0 + q);
            ((float*)&v)[q] = sqrtf(r.x*r.x + r.y*r.y + r.z*r.z);
        }
    } else {                            // ---- r_ij ----
        unsigned u  = g - 3u*S4;        // float4 index within r section
        unsigned f0 = u * 4u;           // first float index within r section
        unsigned p0 = f0 / 3u;
        unsigned c0 = f0 - 3u*p0;       // starting component of pair p0
        float3 a = pair_r(pos, p0);
        float3 b = pair_r(pos, p0 + 1u); // p0+1 <= NP-1 always (see layout proof)
        if (c0 == 0u)      v = make_float4(a.x, a.y, a.z, b.x);
        else if (c0 == 1u) v = make_float4(a.y, a.z, b.x, b.y);
        else               v = make_float4(a.z, b.x, b.y, b.z);
    }

    ((float4*)out)[g] = v;
}

extern "C" void kernel_launch(void* const* d_in, const int* in_sizes, int n_in,
                              void* d_out, int out_size, void* d_ws, size_t ws_size,
                              hipStream_t stream) {
    const float* pos = (const float*)d_in[0];
    float* out = (float*)d_out;
    pairlist_kernel<<<NB, 256, 0, stream>>>(pos, out);
}

// Round 5
// 51.212 us; speedup vs baseline: 1.6705x; 1.6705x over previous
//
#include <hip/hip_runtime.h>

// Pairlist: 1024 molecules x 100 atoms, all ordered pairs i != j.
// 9900 pairs/molecule, NP = 10,137,600 pairs.
//
// Output (float32, flat): [0,NP)=i  [NP,2NP)=j  [2NP,3NP)=d  [3NP,6NP)=r_ij
//
// R0's per-pair mapping (best so far, 41.5 us) restructured as a grid-stride
// kernel: 1980 blocks x 256 threads = 506,880 long-lived threads, 20 pairs
// each (506,880 * 20 = NP exactly, no tail). Per iteration the lane->address
// mapping is identical to R0 (lane-contiguous dword stores per stream);
// the change is memset-shaped execution: few waves, long-lived, no
// workgroup launch/drain churn across 39,600 blocks.

#define N_MOL 1024
#define APM   100u
#define PPM   9900u                  // pairs per molecule
#define NP    10137600u              // total pairs
#define NTH   506880u                // 1980 blocks * 256 threads
#define ITERS 20u                    // NTH * ITERS == NP
#define NB    1980

__global__ __launch_bounds__(256) void pairlist_kernel(
    const float* __restrict__ pos,   // (102400, 3)
    float* __restrict__ out)
{
    unsigned t = blockIdx.x * 256u + threadIdx.x;
    float* __restrict__ oi = out;
    float* __restrict__ oj = out + (size_t)NP;
    float* __restrict__ od = out + (size_t)2 * NP;
    float* __restrict__ orr = out + (size_t)3 * NP;

    #pragma unroll 2
    for (unsigned it = 0; it < ITERS; ++it) {
        unsigned p = t + it * NTH;

        unsigned m  = p / PPM;
        unsigned r  = p - m * PPM;
        unsigned il = r / 99u;
        unsigned k  = r - il * 99u;
        unsigned jl = k + (k >= il ? 1u : 0u);
        unsigned base = m * APM;
        unsigned i = base + il;
        unsigned j = base + jl;

        float xi = pos[3u*i+0u], yi = pos[3u*i+1u], zi = pos[3u*i+2u];
        float xj = pos[3u*j+0u], yj = pos[3u*j+1u], zj = pos[3u*j+2u];
        float rx = xj - xi, ry = yj - yi, rz = zj - zi;
        float d  = sqrtf(rx*rx + ry*ry + rz*rz);

        oi[p] = (float)i;
        oj[p] = (float)j;
        od[p] = d;
        size_t b = (size_t)3 * (size_t)p;
        orr[b + 0] = rx;
        orr[b + 1] = ry;
        orr[b + 2] = rz;
    }
}

extern "C" void kernel_launch(void* const* d_in, const int* in_sizes, int n_in,
                              void* d_out, int out_size, void* d_ws, size_t ws_size,
                              hipStream_t stream) {
    const float* pos = (const float*)d_in[0];
    float* out = (float*)d_out;
    pairlist_kernel<<<NB, 256, 0, stream>>>(pos, out);
}

// Round 6
// 46.282 us; speedup vs baseline: 1.8485x; 1.1065x over previous
//
#include <hip/hip_runtime.h>

// Pairlist: 1024 molecules x 100 atoms, all ordered pairs i != j.
// 9900 pairs/molecule, NP = 10,137,600 pairs.
//
// Output (float32, flat): [0,NP)=i  [NP,2NP)=j  [2NP,3NP)=d  [3NP,6NP)=r_ij
//
// Structure = R0 (best: 41.5 us, 5.86 TB/s): 1 thread = 1 pair, scalar
// dword stores (lane-contiguous per stream), 39,600 blocks in dispatch
// order. R1-R4 established that vector stores, LDS-staged coalescing,
// single-sweep layout, and grid-stride all REGRESS vs this.
//
// One change vs R0: nontemporal stores (output is write-once, never
// re-read) to avoid streaming 243 MB through L2 / evicting the
// L2-resident positions working set.

#define N_MOL 1024
#define APM   100u
#define PPM   9900u                  // pairs per molecule
#define NP    10137600u              // total pairs

__global__ __launch_bounds__(256) void pairlist_kernel(
    const float* __restrict__ pos,   // (102400, 3)
    float* __restrict__ out)
{
    unsigned p = blockIdx.x * 256u + threadIdx.x;
    if (p >= NP) return;

    unsigned m  = p / PPM;
    unsigned r  = p - m * PPM;
    unsigned il = r / 99u;
    unsigned k  = r - il * 99u;
    unsigned jl = k + (k >= il ? 1u : 0u);
    unsigned base = m * APM;
    unsigned i = base + il;
    unsigned j = base + jl;

    float xi = pos[3u*i+0u], yi = pos[3u*i+1u], zi = pos[3u*i+2u];
    float xj = pos[3u*j+0u], yj = pos[3u*j+1u], zj = pos[3u*j+2u];
    float rx = xj - xi, ry = yj - yi, rz = zj - zi;
    float d  = sqrtf(rx*rx + ry*ry + rz*rz);

    __builtin_nontemporal_store((float)i, out + p);
    __builtin_nontemporal_store((float)j, out + (size_t)NP + p);
    __builtin_nontemporal_store(d,        out + (size_t)2*NP + p);
    float* rr = out + (size_t)3*NP + (size_t)3*p;
    __builtin_nontemporal_store(rx, rr + 0);
    __builtin_nontemporal_store(ry, rr + 1);
    __builtin_nontemporal_store(rz, rr + 2);
}

extern "C" void kernel_launch(void* const* d_in, const int* in_sizes, int n_in,
                              void* d_out, int out_size, void* d_ws, size_t ws_size,
                              hipStream_t stream) {
    const float* pos = (const float*)d_in[0];
    float* out = (float*)d_out;
    int nblocks = (NP + 255u) / 256u;   // 39,600
    pairlist_kernel<<<nblocks, 256, 0, stream>>>(pos, out);
}

// Round 7
// 41.441 us; speedup vs baseline: 2.0644x; 1.1168x over previous
//
#include <hip/hip_runtime.h>

// Pairlist: 1024 molecules x 100 atoms, all ordered pairs i != j within each
// molecule. Structure is static: 9900 pairs/molecule, 10,137,600 total.
//
// Output layout (all float32, concatenated flat in reference return order):
//   [0          , NP)        : pair_indices row 0 (i), as float
//   [NP         , 2*NP)      : pair_indices row 1 (j), as float
//   [2*NP       , 3*NP)      : d_ij
//   [3*NP       , 6*NP)      : r_ij (n_pairs, 3) row-major
//
// FINAL (R0 structure, 41.5 us = 5.86 TB/s effective, 93% of the 6.3 TB/s
// achievable-copy ceiling; 243.3 MB mandatory writes -> 38.6 us floor).
// Refuted alternatives (all regressed): float4 stores per-lane (R1, 50.3),
// LDS-staged coalesced stores (R2, 45.4), single-sweep memset-shaped layout
// (R3, 85.6), grid-stride long-lived waves (R4, 51.2), nontemporal stores
// (R5, 46.3). Plain scalar dword stores + dispatch-order block locality +
// L2 write-combining is the best DRAM citizen for this 4-stream pattern.

#define N_MOL 1024
#define APM   100              // atoms per molecule
#define PPM   (APM * (APM-1))  // 9900 pairs per molecule
#define NP    (N_MOL * PPM)    // 10,137,600 total pairs

__global__ __launch_bounds__(256) void pairlist_kernel(
    const float* __restrict__ pos,   // (102400, 3)
    float* __restrict__ out)
{
    int p = blockIdx.x * blockDim.x + threadIdx.x;
    if (p >= NP) return;

    unsigned up = (unsigned)p;
    unsigned m  = up / (unsigned)PPM;          // molecule
    unsigned r  = up - m * (unsigned)PPM;
    unsigned il = r / 99u;                     // local i
    unsigned k  = r - il * 99u;                // pair slot within i's row
    unsigned jl = k + (k >= il ? 1u : 0u);     // local j (skip j == i)
    unsigned i  = m * (unsigned)APM + il;
    unsigned j  = m * (unsigned)APM + jl;

    // positions: tiny working set (1.2 KB per molecule, 1.2 MB total) -> cached
    float xi = pos[3u*i + 0u], yi = pos[3u*i + 1u], zi = pos[3u*i + 2u];
    float xj = pos[3u*j + 0u], yj = pos[3u*j + 1u], zj = pos[3u*j + 2u];

    float rx = xj - xi, ry = yj - yi, rz = zj - zi;
    float d  = sqrtf(rx*rx + ry*ry + rz*rz);

    out[p]          = (float)i;
    out[NP + p]     = (float)j;
    out[2*NP + p]   = d;

    float* rr = out + (size_t)3 * NP;
    size_t b = (size_t)3 * (size_t)p;
    rr[b + 0] = rx;
    rr[b + 1] = ry;
    rr[b + 2] = rz;
}

extern "C" void kernel_launch(void* const* d_in, const int* in_sizes, int n_in,
                              void* d_out, int out_size, void* d_ws, size_t ws_size,
                              hipStream_t stream) {
    const float* pos = (const float*)d_in[0];
    float* out = (float*)d_out;
    int nblocks = (NP + 255) / 256;
    pairlist_kernel<<<nblocks, 256, 0, stream>>>(pos, out);
}